// Round 4
// baseline (710.534 us; speedup 1.0000x reference)
//
#include <hip/hip_runtime.h>
#include <hip/hip_bf16.h>

// KeyDecider: x (64, 34, 256, 256) f32.  For each (b, c<17):
//   w  = softmax(x[b,c].flatten())           (N = 65536)
//   ki = round(sum(w * arange(N)))
//   out[b,c] = { ki mod 256, floor(ki/256), sum(w * x[b,c+17].flatten()) }
//
// Softmax as a ratio needs no max pass: ki = (Σ e^h·p)/(Σ e^h). Inputs are
// N(0,1) so e^h <= ~e^6 — no overflow in f32; accumulate in f64 so the
// round-half-even of ki matches the numpy reference.

#define KD_K 17
#define KD_C 34
#define KD_N 65536
#define KD_N4 (KD_N / 4)
#define KD_THREADS 256

__global__ __launch_bounds__(KD_THREADS)
void kd_kernel(const float* __restrict__ x, float* __restrict__ out) {
    const int pair = blockIdx.x;           // 0 .. 64*17-1
    const int b = pair / KD_K;
    const int c = pair % KD_K;

    const float4* __restrict__ h4 =
        reinterpret_cast<const float4*>(x + (size_t)(b * KD_C + c) * KD_N);
    const float4* __restrict__ v4 =
        reinterpret_cast<const float4*>(x + (size_t)(b * KD_C + c + KD_K) * KD_N);

    double s = 0.0, sp = 0.0, sv = 0.0;

    // 64 iterations/thread; consecutive threads -> consecutive float4s (coalesced).
    #pragma unroll 4
    for (int j = threadIdx.x; j < KD_N4; j += KD_THREADS) {
        const float4 h = h4[j];
        const float4 v = v4[j];
        const float e0 = expf(h.x);
        const float e1 = expf(h.y);
        const float e2 = expf(h.z);
        const float e3 = expf(h.w);
        const double i0 = (double)(4 * j);
        s  += ((double)e0 + (double)e1) + ((double)e2 + (double)e3);
        sp += ((double)e0 * i0 + (double)e1 * (i0 + 1.0)) +
              ((double)e2 * (i0 + 2.0) + (double)e3 * (i0 + 3.0));
        sv += ((double)e0 * (double)v.x + (double)e1 * (double)v.y) +
              ((double)e2 * (double)v.z + (double)e3 * (double)v.w);
    }

    // Wave (64-lane) butterfly reduction.
    #pragma unroll
    for (int off = 32; off > 0; off >>= 1) {
        s  += __shfl_xor(s,  off);
        sp += __shfl_xor(sp, off);
        sv += __shfl_xor(sv, off);
    }

    // Combine the 4 wave partials through LDS.
    __shared__ double ls[3][4];
    const int wid  = threadIdx.x >> 6;
    const int lane = threadIdx.x & 63;
    if (lane == 0) {
        ls[0][wid] = s;
        ls[1][wid] = sp;
        ls[2][wid] = sv;
    }
    __syncthreads();

    if (threadIdx.x == 0) {
        const double S  = (ls[0][0] + ls[0][1]) + (ls[0][2] + ls[0][3]);
        const double SP = (ls[1][0] + ls[1][1]) + (ls[1][2] + ls[1][3]);
        const double SV = (ls[2][0] + ls[2][1]) + (ls[2][2] + ls[2][3]);

        const double ki   = rint(SP / S);          // round half-to-even == np.round
        const double row  = floor(ki * (1.0 / 256.0));
        const double co_x = ki - 256.0 * row;      // ki mod 256  (ki >= 0)
        const double co_y = row;                   // floor(ki/256)

        float* o = out + (size_t)(b * KD_K + c) * 3;
        o[0] = (float)co_x;
        o[1] = (float)co_y;
        o[2] = (float)(SV / S);
    }
}

extern "C" void kernel_launch(void* const* d_in, const int* in_sizes, int n_in,
                              void* d_out, int out_size, void* d_ws, size_t ws_size,
                              hipStream_t stream) {
    const float* x = (const float*)d_in[0];
    float* out = (float*)d_out;
    kd_kernel<<<dim3(64 * KD_K), dim3(KD_THREADS), 0, stream>>>(x, out);
}

// Round 7
// 693.654 us; speedup vs baseline: 1.0243x; 1.0243x over previous
//
#include <hip/hip_runtime.h>
#include <hip/hip_bf16.h>

// KeyDecider: x (64, 34, 256, 256) f32.  For each (b, c<17):
//   w  = softmax(x[b,c].flatten())           (N = 65536)
//   ki = round(sum(w * arange(N)))
//   out[b,c] = { ki mod 256, floor(ki/256), sum(w * x[b,c+17].flatten()) }
//
// Ratio softmax (no max pass needed: N(0,1) inputs bound e^h <= ~e^6), f64
// accumulation so rint(ki) matches np.round to within the reference's own
// f32 noise.  Two-stage: 2176 half-unit blocks -> f64 partials in d_ws,
// then a tiny combine kernel.  More waves/CU + better tail balance than
// 1088 blocks (4.25/CU -> 8.5/CU).

#define KD_K 17
#define KD_C 34
#define KD_N 65536
#define KD_SPLIT 2
#define KD_HALF_N  (KD_N / KD_SPLIT)        // 32768 elements per half
#define KD_HALF_N4 (KD_HALF_N / 4)          // 8192 float4 per half
#define KD_THREADS 256
#define KD_UNITS  (64 * KD_K)               // 1088
#define KD_BLOCKS1 (KD_UNITS * KD_SPLIT)    // 2176

// Native clang vector type: required by __builtin_nontemporal_load
// (HIP_vector_type<float,4> is a struct and is rejected).
typedef float f32x4 __attribute__((ext_vector_type(4)));

__global__ __launch_bounds__(KD_THREADS)
void kd_stage1(const float* __restrict__ x, double* __restrict__ ws) {
    const int blk  = blockIdx.x;
    const int unit = blk / KD_SPLIT;        // 0 .. 1087
    const int half = blk % KD_SPLIT;
    const int b = unit / KD_K;
    const int c = unit % KD_K;

    const f32x4* __restrict__ h4 = reinterpret_cast<const f32x4*>(
        x + (size_t)(b * KD_C + c) * KD_N + half * KD_HALF_N);
    const f32x4* __restrict__ v4 = reinterpret_cast<const f32x4*>(
        x + (size_t)(b * KD_C + c + KD_K) * KD_N + half * KD_HALF_N);
    const int elem0 = half * KD_HALF_N;

    double s = 0.0, sp = 0.0, sv = 0.0;

    // 32 iterations/thread; consecutive threads -> consecutive float4s.
    // Read-once data: nontemporal to avoid L2 pollution.
    #pragma unroll 4
    for (int j = threadIdx.x; j < KD_HALF_N4; j += KD_THREADS) {
        const f32x4 h = __builtin_nontemporal_load(h4 + j);
        const f32x4 v = __builtin_nontemporal_load(v4 + j);
        const float e0 = expf(h.x);
        const float e1 = expf(h.y);
        const float e2 = expf(h.z);
        const float e3 = expf(h.w);
        const double i0 = (double)(elem0 + 4 * j);
        s  += ((double)e0 + (double)e1) + ((double)e2 + (double)e3);
        sp += ((double)e0 * i0 + (double)e1 * (i0 + 1.0)) +
              ((double)e2 * (i0 + 2.0) + (double)e3 * (i0 + 3.0));
        sv += ((double)e0 * (double)v.x + (double)e1 * (double)v.y) +
              ((double)e2 * (double)v.z + (double)e3 * (double)v.w);
    }

    // Wave (64-lane) butterfly reduction.
    #pragma unroll
    for (int off = 32; off > 0; off >>= 1) {
        s  += __shfl_xor(s,  off);
        sp += __shfl_xor(sp, off);
        sv += __shfl_xor(sv, off);
    }

    // Combine the 4 wave partials through LDS; thread 0 writes the triple.
    __shared__ double ls[3][4];
    const int wid  = threadIdx.x >> 6;
    const int lane = threadIdx.x & 63;
    if (lane == 0) {
        ls[0][wid] = s;
        ls[1][wid] = sp;
        ls[2][wid] = sv;
    }
    __syncthreads();

    if (threadIdx.x == 0) {
        double* w = ws + (size_t)blk * 4;   // stride 4 doubles (32B) per block
        w[0] = (ls[0][0] + ls[0][1]) + (ls[0][2] + ls[0][3]);
        w[1] = (ls[1][0] + ls[1][1]) + (ls[1][2] + ls[1][3]);
        w[2] = (ls[2][0] + ls[2][1]) + (ls[2][2] + ls[2][3]);
    }
}

__global__ __launch_bounds__(KD_THREADS)
void kd_stage2(const double* __restrict__ ws, float* __restrict__ out) {
    const int u = blockIdx.x * KD_THREADS + threadIdx.x;
    if (u >= KD_UNITS) return;

    const double* w = ws + (size_t)u * KD_SPLIT * 4;
    const double S  = w[0] + w[4];
    const double SP = w[1] + w[5];
    const double SV = w[2] + w[6];

    const double ki   = rint(SP / S);            // round half-to-even == np.round
    const double row  = floor(ki * (1.0 / 256.0));
    const double co_x = ki - 256.0 * row;        // ki mod 256  (ki >= 0)

    float* o = out + (size_t)u * 3;
    o[0] = (float)co_x;
    o[1] = (float)row;
    o[2] = (float)(SV / S);
}

extern "C" void kernel_launch(void* const* d_in, const int* in_sizes, int n_in,
                              void* d_out, int out_size, void* d_ws, size_t ws_size,
                              hipStream_t stream) {
    const float* x = (const float*)d_in[0];
    float* out = (float*)d_out;
    double* ws = (double*)d_ws;   // 2176 * 4 doubles = 68 KB << ws_size

    kd_stage1<<<dim3(KD_BLOCKS1), dim3(KD_THREADS), 0, stream>>>(x, ws);
    kd_stage2<<<dim3((KD_UNITS + KD_THREADS - 1) / KD_THREADS),
                dim3(KD_THREADS), 0, stream>>>(ws, out);
}